// Round 1
// baseline (127.006 us; speedup 1.0000x reference)
//
#include <hip/hip_runtime.h>

// ActorCriticMSECriterionAIC: masked MSE criterion.
// Inputs: seq [B,S] int32, value [B,S] f32, reward [B,S] f32 (B=65536, S=256).
// Outputs (3 f32 scalars): loss = sum(diff^2 * mask)/sum(mask),
//   diff_mean = mean(reward - value), sample_mean = mean(reward).
// mask[b,j] = 1 iff j==0 or seq[b,0..j-1] all nonzero  =>  per row: ones for
// j < count, count = min(first_zero_idx + 1, S)  (S if no zero in the row).
//
// Wave-per-row layout: 64 lanes x 4 elems (int4/float4) = 256 = S, fully
// coalesced. f64 accumulation (f32 would lose ~1e-7 rel per add over 1.6e7
// adds -> unsafe vs 2.67e-2 threshold on a ~1.33 value... actually the risk
// is the 2.2e7-magnitude sum; f64 makes it exact to ~1e-9).

__global__ __launch_bounds__(256) void ac_mse_reduce(
    const int* __restrict__ seq,
    const float* __restrict__ value,
    const float* __restrict__ reward,
    double* __restrict__ ws,
    int B, int S) {

    const int lane = threadIdx.x & 63;
    const int wave_in_block = threadIdx.x >> 6;
    const int waves_per_block = blockDim.x >> 6;
    const int global_wave = blockIdx.x * waves_per_block + wave_in_block;
    const int total_waves = gridDim.x * waves_per_block;

    double acc_sq = 0.0;   // sum of masked diff^2
    double acc_cnt = 0.0;  // sum of mask
    double acc_sr = 0.0;   // sum of reward (all elements)
    double acc_sv = 0.0;   // sum of value  (all elements)

    for (int row = global_wave; row < B; row += total_waves) {
        const size_t base = (size_t)row * (size_t)S + (size_t)(lane * 4);
        const int4   s = *reinterpret_cast<const int4*>(seq + base);
        const float4 v = *reinterpret_cast<const float4*>(value + base);
        const float4 r = *reinterpret_cast<const float4*>(reward + base);

        // local first-zero position within this lane's 4 elements (4 = none)
        int p = 4;
        if (s.w == 0) p = 3;
        if (s.z == 0) p = 2;
        if (s.y == 0) p = 1;
        if (s.x == 0) p = 0;
        int cand = (p < 4) ? (lane * 4 + p) : 1024;
        // wave-wide min over 64 lanes (wave = 64 on CDNA!)
        #pragma unroll
        for (int off = 32; off > 0; off >>= 1) {
            int o = __shfl_xor(cand, off);
            cand = (o < cand) ? o : cand;
        }
        int count = cand + 1;          // ones up to and including first zero
        if (count > S) count = S;      // no zero -> full row

        const float d0 = r.x - v.x;
        const float d1 = r.y - v.y;
        const float d2 = r.z - v.z;
        const float d3 = r.w - v.w;
        const int j = lane * 4;
        float lsq = 0.0f;              // <=4 adds in f32: exact enough
        if (j + 0 < count) lsq += d0 * d0;
        if (j + 1 < count) lsq += d1 * d1;
        if (j + 2 < count) lsq += d2 * d2;
        if (j + 3 < count) lsq += d3 * d3;

        acc_sq += (double)lsq;
        acc_sr += (double)((r.x + r.y) + (r.z + r.w));
        acc_sv += (double)((v.x + v.y) + (v.z + v.w));
        if (lane == 0) acc_cnt += (double)count;
    }

    // wave reduction (doubles shuffle as 2x32b; fine on HIP)
    #pragma unroll
    for (int off = 32; off > 0; off >>= 1) {
        acc_sq  += __shfl_down(acc_sq,  off);
        acc_cnt += __shfl_down(acc_cnt, off);
        acc_sr  += __shfl_down(acc_sr,  off);
        acc_sv  += __shfl_down(acc_sv,  off);
    }

    __shared__ double sm[4][8];  // up to 8 waves/block (block<=512)
    if (lane == 0) {
        sm[0][wave_in_block] = acc_sq;
        sm[1][wave_in_block] = acc_cnt;
        sm[2][wave_in_block] = acc_sr;
        sm[3][wave_in_block] = acc_sv;
    }
    __syncthreads();
    if (threadIdx.x == 0) {
        double t0 = 0, t1 = 0, t2 = 0, t3 = 0;
        for (int w = 0; w < waves_per_block; ++w) {
            t0 += sm[0][w]; t1 += sm[1][w]; t2 += sm[2][w]; t3 += sm[3][w];
        }
        atomicAdd(&ws[0], t0);  // CAS loop is fine: 2048 blocks x 4 adds
        atomicAdd(&ws[1], t1);
        atomicAdd(&ws[2], t2);
        atomicAdd(&ws[3], t3);
    }
}

__global__ void ac_mse_final(const double* __restrict__ ws,
                             float* __restrict__ out, double inv_n) {
    if (threadIdx.x == 0 && blockIdx.x == 0) {
        out[0] = (float)(ws[0] / ws[1]);            // loss
        out[1] = (float)((ws[2] - ws[3]) * inv_n);  // mean(reward - value)
        out[2] = (float)(ws[2] * inv_n);            // mean(reward)
    }
}

extern "C" void kernel_launch(void* const* d_in, const int* in_sizes, int n_in,
                              void* d_out, int out_size, void* d_ws, size_t ws_size,
                              hipStream_t stream) {
    const int*   seq    = (const int*)d_in[0];
    const float* value  = (const float*)d_in[1];
    const float* reward = (const float*)d_in[2];
    float*  out = (float*)d_out;
    double* ws  = (double*)d_ws;

    const int S = 256;
    const long long total = (long long)in_sizes[0];
    const int B = (int)(total / S);

    // workspace accumulators must start at zero every call (harness poisons
    // d_ws once and never re-poisons between replays)
    hipMemsetAsync(ws, 0, 4 * sizeof(double), stream);

    const int block = 256;                 // 4 waves/block
    const int grid  = 2048;                // grid-stride: 8 rows per wave
    ac_mse_reduce<<<grid, block, 0, stream>>>(seq, value, reward, ws, B, S);
    ac_mse_final<<<1, 64, 0, stream>>>(ws, out, 1.0 / (double)total);
}

// Round 2
// 41.939 us; speedup vs baseline: 3.0284x; 3.0284x over previous
//
#include <hip/hip_runtime.h>

// ActorCriticMSECriterionAIC: masked MSE criterion.
// Inputs: seq [B,S] int32, value [B,S] f32, reward [B,S] f32 (B=65536, S=256).
// Outputs (3 f32): loss = sum(diff^2*mask)/sum(mask), mean(reward-value), mean(reward).
// mask[b,j] = 1 iff j < count(b), count = first_zero_idx+1 (S if no zero).
//
// R1 changes vs R0 (137us, 9% HBM, VALU 6% -- latency/serialization bound):
//  - NO global atomics: per-block partials -> d_ws (SoA), 1-block finalize.
//    (f64 atomicAdd on shared addresses suspected CAS-serialized tail.)
//  - first-zero via one __ballot + one __shfl (was 6-step shuffle-min chain).
//  - 2-row unroll per wave iteration for memory-level parallelism.
//  - no hipMemsetAsync needed (all partial slots written unconditionally).

__device__ __forceinline__ void row_accum(
    const int4 s, const float4 v, const float4 r, int lane, int S,
    double& acc_sq, double& acc_cnt, double& acc_sr, double& acc_sv) {

    // position of first zero within this lane's 4 elements (4 = none)
    int p = 4;
    if (s.w == 0) p = 3;
    if (s.z == 0) p = 2;
    if (s.y == 0) p = 1;
    if (s.x == 0) p = 0;

    // first zero across the wave: ballot (64-bit on CDNA) + one shfl
    unsigned long long zmask = __ballot(p < 4);
    int count = S;
    if (zmask) {                                   // wave-uniform branch
        const int fl = __ffsll((unsigned long long)zmask) - 1;
        const int pf = __shfl(p, fl);
        count = fl * 4 + pf + 1;
    }

    const float d0 = r.x - v.x;
    const float d1 = r.y - v.y;
    const float d2 = r.z - v.z;
    const float d3 = r.w - v.w;
    const int j = lane * 4;
    float lsq = 0.0f;
    if (j + 0 < count) lsq += d0 * d0;
    if (j + 1 < count) lsq += d1 * d1;
    if (j + 2 < count) lsq += d2 * d2;
    if (j + 3 < count) lsq += d3 * d3;

    acc_sq += (double)lsq;
    acc_sr += (double)((r.x + r.y) + (r.z + r.w));
    acc_sv += (double)((v.x + v.y) + (v.z + v.w));
    if (lane == 0) acc_cnt += (double)count;
}

__global__ __launch_bounds__(256) void ac_mse_reduce(
    const int* __restrict__ seq,
    const float* __restrict__ value,
    const float* __restrict__ reward,
    double* __restrict__ part,   // SoA: part[c*nb + blockIdx.x], c in 0..3
    int B, int S, int nb) {

    const int lane = threadIdx.x & 63;
    const int wave_in_block = threadIdx.x >> 6;
    const int global_wave = blockIdx.x * 4 + wave_in_block;
    const int total_waves = nb * 4;

    double acc_sq = 0.0, acc_cnt = 0.0, acc_sr = 0.0, acc_sv = 0.0;

    // two rows in flight per iteration (6 x 16B loads outstanding)
    for (int row = global_wave; row < B; row += 2 * total_waves) {
        const int row2 = row + total_waves;           // wave-uniform
        const size_t base1 = (size_t)row * (size_t)S + (size_t)(lane * 4);
        const int4   s1 = *reinterpret_cast<const int4*>(seq + base1);
        const float4 v1 = *reinterpret_cast<const float4*>(value + base1);
        const float4 r1 = *reinterpret_cast<const float4*>(reward + base1);
        int4 s2; float4 v2, r2;
        const bool has2 = (row2 < B);
        if (has2) {
            const size_t base2 = (size_t)row2 * (size_t)S + (size_t)(lane * 4);
            s2 = *reinterpret_cast<const int4*>(seq + base2);
            v2 = *reinterpret_cast<const float4*>(value + base2);
            r2 = *reinterpret_cast<const float4*>(reward + base2);
        }
        row_accum(s1, v1, r1, lane, S, acc_sq, acc_cnt, acc_sr, acc_sv);
        if (has2)
            row_accum(s2, v2, r2, lane, S, acc_sq, acc_cnt, acc_sr, acc_sv);
    }

    // wave reduction
    #pragma unroll
    for (int off = 32; off > 0; off >>= 1) {
        acc_sq  += __shfl_down(acc_sq,  off);
        acc_cnt += __shfl_down(acc_cnt, off);
        acc_sr  += __shfl_down(acc_sr,  off);
        acc_sv  += __shfl_down(acc_sv,  off);
    }

    __shared__ double sm[4][4];
    if (lane == 0) {
        sm[0][wave_in_block] = acc_sq;
        sm[1][wave_in_block] = acc_cnt;
        sm[2][wave_in_block] = acc_sr;
        sm[3][wave_in_block] = acc_sv;
    }
    __syncthreads();
    if (threadIdx.x == 0) {
        part[0 * (size_t)nb + blockIdx.x] = sm[0][0] + sm[0][1] + sm[0][2] + sm[0][3];
        part[1 * (size_t)nb + blockIdx.x] = sm[1][0] + sm[1][1] + sm[1][2] + sm[1][3];
        part[2 * (size_t)nb + blockIdx.x] = sm[2][0] + sm[2][1] + sm[2][2] + sm[2][3];
        part[3 * (size_t)nb + blockIdx.x] = sm[3][0] + sm[3][1] + sm[3][2] + sm[3][3];
    }
}

// One block, 4 waves: wave c reduces component c over nb block-partials.
__global__ __launch_bounds__(256) void ac_mse_final(
    const double* __restrict__ part, float* __restrict__ out,
    int nb, double inv_n) {

    const int lane = threadIdx.x & 63;
    const int c = threadIdx.x >> 6;
    const double* p = part + (size_t)c * nb;

    // 4 independent accumulators for ILP over the L2-resident partials
    double a0 = 0, a1 = 0, a2 = 0, a3 = 0;
    int b = lane;
    for (; b + 192 < nb; b += 256) {
        a0 += p[b]; a1 += p[b + 64]; a2 += p[b + 128]; a3 += p[b + 192];
    }
    for (; b < nb; b += 64) a0 += p[b];
    double a = (a0 + a1) + (a2 + a3);

    #pragma unroll
    for (int off = 32; off > 0; off >>= 1) a += __shfl_down(a, off);

    __shared__ double sm[4];
    if (lane == 0) sm[c] = a;
    __syncthreads();
    if (threadIdx.x == 0) {
        out[0] = (float)(sm[0] / sm[1]);            // loss
        out[1] = (float)((sm[2] - sm[3]) * inv_n);  // mean(reward - value)
        out[2] = (float)(sm[2] * inv_n);            // mean(reward)
    }
}

extern "C" void kernel_launch(void* const* d_in, const int* in_sizes, int n_in,
                              void* d_out, int out_size, void* d_ws, size_t ws_size,
                              hipStream_t stream) {
    const int*   seq    = (const int*)d_in[0];
    const float* value  = (const float*)d_in[1];
    const float* reward = (const float*)d_in[2];
    float*  out = (float*)d_out;
    double* ws  = (double*)d_ws;

    const int S = 256;
    const long long total = (long long)in_sizes[0];
    const int B = (int)(total / S);

    int nb = 4096;                                  // 2x wave capacity
    const size_t need = (size_t)nb * 4 * sizeof(double);
    if (ws_size < need) nb = (int)(ws_size / (4 * sizeof(double)));

    ac_mse_reduce<<<nb, 256, 0, stream>>>(seq, value, reward, ws, B, S, nb);
    ac_mse_final<<<1, 256, 0, stream>>>(ws, out, nb, 1.0 / (double)total);
}